// Round 1
// baseline (102.945 us; speedup 1.0000x reference)
//
#include <hip/hip_runtime.h>
#include <math.h>

// ScorePredictor: out[e] = sigmoid(x[src[e]] . w_s + x[dst[e]] . w_d + b)
// Factored: p_s[n] = x[n].w_s ; p_d[n] = x[n].w_d  (one coalesced pass over x)
// then     out[e] = sigmoid(p_s[src[e]] + p_d[dst[e]] + b)  (gathers hit L2)

#define DIM 128

// One 32-lane half-wave per node. Each lane loads one float4 (32 lanes * 16B
// = 512B = exactly one row), computes partial dots vs w_s and w_d, then a
// 32-wide shuffle butterfly reduces both sums.
__global__ __launch_bounds__(256) void proj_kernel(
    const float* __restrict__ x,
    const float* __restrict__ W,   // 256 floats: [w_s | w_d]
    float* __restrict__ ps,
    float* __restrict__ pd,
    int n_nodes)
{
    const int half = threadIdx.x >> 5;     // 0..7 half-waves per block
    const int lane = threadIdx.x & 31;
    const int node = blockIdx.x * 8 + half;
    if (node >= n_nodes) return;

    const float4* x4 = (const float4*)x + (size_t)node * (DIM / 4) + lane;
    float4 v = *x4;

    const float4* w4 = (const float4*)W;
    float4 ws = w4[lane];        // w_s[4*lane .. 4*lane+3]
    float4 wd = w4[32 + lane];   // w_d[4*lane .. 4*lane+3]

    float s = v.x * ws.x + v.y * ws.y + v.z * ws.z + v.w * ws.w;
    float d = v.x * wd.x + v.y * wd.y + v.z * wd.z + v.w * wd.w;

    #pragma unroll
    for (int off = 16; off > 0; off >>= 1) {
        s += __shfl_down(s, off, 32);
        d += __shfl_down(d, off, 32);
    }
    if (lane == 0) {
        ps[node] = s;
        pd[node] = d;
    }
}

__global__ __launch_bounds__(256) void edge_kernel(
    const int* __restrict__ src,
    const int* __restrict__ dst,
    const float* __restrict__ ps,
    const float* __restrict__ pd,
    const float* __restrict__ b,
    float* __restrict__ out,
    int n_edges)
{
    const int e = blockIdx.x * blockDim.x + threadIdx.x;
    if (e >= n_edges) return;
    const float z = ps[src[e]] + pd[dst[e]] + b[0];
    out[e] = 1.0f / (1.0f + __expf(-z));
}

extern "C" void kernel_launch(void* const* d_in, const int* in_sizes, int n_in,
                              void* d_out, int out_size, void* d_ws, size_t ws_size,
                              hipStream_t stream) {
    const float* x   = (const float*)d_in[0];
    const int*   src = (const int*)d_in[1];
    const int*   dst = (const int*)d_in[2];
    const float* W   = (const float*)d_in[3];
    const float* b   = (const float*)d_in[4];
    float* out = (float*)d_out;

    const int n_nodes = in_sizes[0] / DIM;
    const int n_edges = in_sizes[1];

    float* ps = (float*)d_ws;            // n_nodes floats
    float* pd = ps + n_nodes;            // n_nodes floats  (800 KB total)

    proj_kernel<<<(n_nodes + 7) / 8, 256, 0, stream>>>(x, W, ps, pd, n_nodes);
    edge_kernel<<<(n_edges + 255) / 256, 256, 0, stream>>>(src, dst, ps, pd, b, out, n_edges);
}